// Round 2
// baseline (366.212 us; speedup 1.0000x reference)
//
#include <hip/hip_runtime.h>

// RaggedSelectThreshold: keep rows with xs > 0.5, stably compact pl rows to the
// front of an [N,F] buffer (zero-padded), emit new row splits and scatter idxs.
// Outputs written as float32 values (harness reads d_out as one f32 blob).
//
// d_out layout (floats): [N*F newfeat][B+1 new_rs][N scatter_idxs]
// d_ws layout: [u64 bitmap[(N+63)/64]][int blk_counts[1024]][int blk_off[1024]][int nsel]
//
// 3 kernels:
//   k_count: xs -> mask bitmap + per-1024-row block counts    (~3.3 MB traffic)
//   k_scan : 1 block; scan counts -> blk_off, nsel, new_rs    (tiny; new_rs via
//            bitmap popcount at the <=9 boundary positions — no ranks array)
//   k_move : fused scatter+gather+pad. Blocks [0,nb): compact rows via bitmap,
//            write out_sc + copy payload (float4, 16 lanes/row). Blocks
//            [nb,2nb): zero-pad slots >= nsel and write sentinel sc.

#define THRESH 0.5f
#define RPB 1024   // rows per block (4 chunks of 256 threads)

__global__ void k_count(const float* __restrict__ xs, int N,
                        unsigned long long* __restrict__ bitmap,
                        int* __restrict__ blk_counts) {
    __shared__ int wc[16];                       // [chunk*4 + wave]
    const int tid  = threadIdx.x;
    const int lane = tid & 63, wave = tid >> 6;
    const int base = blockIdx.x * RPB;
    for (int c = 0; c < 4; ++c) {
        int i = base + c * 256 + tid;
        int m = (i < N) && (xs[i] > THRESH);
        unsigned long long bal = __ballot(m);
        if (lane == 0) {
            int rowstart = base + c * 256 + wave * 64;
            if (rowstart < N) bitmap[rowstart >> 6] = bal;
            wc[c * 4 + wave] = __popcll(bal);
        }
    }
    __syncthreads();
    if (tid == 0) {
        int s = 0;
        for (int k = 0; k < 16; ++k) s += wc[k];
        blk_counts[blockIdx.x] = s;
    }
}

__global__ void k_scan(const int* __restrict__ blk_counts, int nblocks,
                       const unsigned long long* __restrict__ bitmap,
                       const int* __restrict__ rs, int nrs, int N,
                       int* __restrict__ blk_off, int* __restrict__ nsel_out,
                       float* __restrict__ out_rs) {
    __shared__ int s[1024];
    const int t = threadIdx.x;
    int v = (t < nblocks) ? blk_counts[t] : 0;
    s[t] = v;
    __syncthreads();
    for (int d = 1; d < 1024; d <<= 1) {          // Hillis-Steele inclusive scan
        int add = (t >= d) ? s[t - d] : 0;
        __syncthreads();
        s[t] += add;
        __syncthreads();
    }
    int n_sel = s[1023];
    if (t < nblocks) blk_off[t] = s[t] - v;        // exclusive prefix
    if (t == 0) nsel_out[0] = n_sel;
    if (t < nrs) {
        int j = rs[t];
        int val;
        if (j >= N)      val = n_sel;
        else if (j <= 0) val = 0;
        else {
            int blk = j >> 10;
            int cnt = (blk == 0) ? 0 : s[blk - 1];           // prefix of full blocks
            for (int w = (blk << 10) >> 6; w < (j >> 6); ++w)
                cnt += __popcll(bitmap[w]);
            int rem = j & 63;
            if (rem) cnt += __popcll(bitmap[j >> 6] & ((1ull << rem) - 1ull));
            val = cnt;
        }
        out_rs[t] = (float)val;                    // int value as f32 (exact <2^24)
    }
}

__global__ void k_move(const float4* __restrict__ pl4,
                       const unsigned long long* __restrict__ bitmap,
                       const int* __restrict__ blk_off,
                       const int* __restrict__ nsel, int N, int nblocks,
                       float4* __restrict__ outf4, float* __restrict__ out_sc) {
    const int tid = threadIdx.x;
    const int b   = blockIdx.x;
    if (b < nblocks) {
        // ---- compaction block: input rows [b*1024, b*1024+1024) ----
        __shared__ unsigned long long w[16];
        __shared__ int wpre[16];                   // excl prefix of word popcounts
        __shared__ int rowid[RPB];                 // input row per local slot
        const int base = b << 10;
        if (tid < 16) {
            int rowstart = base + (tid << 6);
            w[tid] = (rowstart < N) ? bitmap[(base >> 6) + tid] : 0ull;
        }
        __syncthreads();
        if (tid == 0) {
            int acc = 0;
            for (int k = 0; k < 16; ++k) { wpre[k] = acc; acc += __popcll(w[k]); }
        }
        __syncthreads();
        const int off = blk_off[b];
        for (int c = 0; c < 4; ++c) {
            int r = c * 256 + tid;                 // local row
            int i = base + r;
            int k = r >> 6, bit = r & 63;
            unsigned long long bw = w[k];
            if (i < N && ((bw >> bit) & 1ull)) {
                int pre = wpre[k] + (int)__popcll(bw & ((1ull << bit) - 1ull));
                rowid[pre] = i;
                out_sc[off + pre] = (float)i;
            }
        }
        __syncthreads();
        const int cnt = wpre[15] + (int)__popcll(w[15]);
        const int cc  = tid & 15;                  // 16 lanes per row, float4
        for (int p = tid >> 4; p < cnt; p += 16) {
            int src = rowid[p];
            outf4[((size_t)(off + p)) * 16 + cc] = pl4[(size_t)src * 16 + cc];
        }
    } else {
        // ---- pad block: output slots [b2*1024, b2*1024+1024) ----
        const int b2    = b - nblocks;
        const int start = b2 << 10;
        const int ns    = nsel[0];
        const int end   = min(start + RPB, N);
        if (end <= ns) return;
        const int lo = max(start, ns);
        for (int s = lo + tid; s < end; s += 256) out_sc[s] = (float)N;
        const int cc = tid & 15;
        const float4 z = make_float4(0.f, 0.f, 0.f, 0.f);
        for (int p = lo + (tid >> 4); p < end; p += 16)
            outf4[((size_t)p) * 16 + cc] = z;
    }
}

extern "C" void kernel_launch(void* const* d_in, const int* in_sizes, int n_in,
                              void* d_out, int out_size, void* d_ws, size_t ws_size,
                              hipStream_t stream) {
    const float* xs = (const float*)d_in[0];
    const float* pl = (const float*)d_in[1];
    const int*   rs = (const int*)d_in[2];
    const int N   = in_sizes[0];        // 800000
    const int F   = in_sizes[1] / N;    // 64 (k_move assumes 64)
    const int nrs = in_sizes[2];        // B+1 = 9

    float* out      = (float*)d_out;
    float* out_feat = out;
    float* out_rs   = out + (size_t)N * F;
    float* out_sc   = out_rs + nrs;

    const int nwords = (N + 63) / 64;
    unsigned long long* bitmap = (unsigned long long*)d_ws;
    int* blk_counts = (int*)(bitmap + nwords);
    int* blk_off    = blk_counts + 1024;
    int* nsel       = blk_off + 1024;

    const int nblocks = (N + RPB - 1) / RPB;   // 782 (must be <= 1024)

    k_count<<<nblocks,     256,  0, stream>>>(xs, N, bitmap, blk_counts);
    k_scan <<<1,           1024, 0, stream>>>(blk_counts, nblocks, bitmap, rs, nrs, N,
                                              blk_off, nsel, out_rs);
    k_move <<<2 * nblocks, 256,  0, stream>>>((const float4*)pl, bitmap, blk_off, nsel,
                                              N, nblocks, (float4*)out_feat, out_sc);
}